// Round 1
// baseline (693.188 us; speedup 1.0000x reference)
//
#include <hip/hip_runtime.h>

// ---------------------------------------------------------------------------
// GNN: h1 = relu((x + mean_agg(x)) @ W1 + b1)
//      h2 = relu((h1 + mean_agg(h1)) @ W2 + b2)
//      out = h2 @ Wp + bp
// Strategy: build CSR (by target) once per call, then pull-aggregate
// (wave per node, coalesced row gathers, no fp atomics), fp32 tiled GEMM.
// ---------------------------------------------------------------------------

__global__ void degree_kernel(const int* __restrict__ tgt, int* __restrict__ deg, int E) {
    int e = blockIdx.x * 256 + threadIdx.x;
    if (e < E) atomicAdd(&deg[tgt[e]], 1);
}

// block scans 1024 elements (256 thr x 4); writes exclusive prefix + block sum
__global__ void scan1_kernel(const int* __restrict__ deg, int* __restrict__ excl,
                             int* __restrict__ blockSums, int N) {
    __shared__ int sd[256];
    int tid = threadIdx.x;
    int base = blockIdx.x * 1024 + tid * 4;
    int v0 = 0, v1 = 0, v2 = 0, v3 = 0;
    if (base + 3 < N) {
        int4 t = *(const int4*)&deg[base];
        v0 = t.x; v1 = t.y; v2 = t.z; v3 = t.w;
    } else {
        if (base     < N) v0 = deg[base];
        if (base + 1 < N) v1 = deg[base + 1];
        if (base + 2 < N) v2 = deg[base + 2];
    }
    int sum = v0 + v1 + v2 + v3;
    sd[tid] = sum;
    __syncthreads();
    for (int o = 1; o < 256; o <<= 1) {
        int t = (tid >= o) ? sd[tid - o] : 0;
        __syncthreads();
        sd[tid] += t;
        __syncthreads();
    }
    int run = sd[tid] - sum;  // exclusive within block
    if (base     < N) excl[base]     = run; run += v0;
    if (base + 1 < N) excl[base + 1] = run; run += v1;
    if (base + 2 < N) excl[base + 2] = run; run += v2;
    if (base + 3 < N) excl[base + 3] = run;
    if (tid == 255) blockSums[blockIdx.x] = sd[255];
}

__global__ void scan2_kernel(int* blockSums, int nb, int* offsets, int N) {
    if (threadIdx.x == 0 && blockIdx.x == 0) {
        int run = 0;
        for (int b = 0; b < nb; ++b) { int t = blockSums[b]; blockSums[b] = run; run += t; }
        offsets[N] = run;
    }
}

__global__ void scan3_kernel(int* __restrict__ offsets, int* __restrict__ cursor,
                             const int* __restrict__ blockSums, int N) {
    int tid = threadIdx.x;
    int base = blockIdx.x * 1024 + tid * 4;
    int bs = blockSums[blockIdx.x];
#pragma unroll
    for (int i = 0; i < 4; ++i) {
        int idx = base + i;
        if (idx < N) { int o = offsets[idx] + bs; offsets[idx] = o; cursor[idx] = o; }
    }
}

__global__ void fill_csr_kernel(const int* __restrict__ src, const int* __restrict__ tgt,
                                int* __restrict__ cursor, int* __restrict__ csr, int E) {
    int e = blockIdx.x * 256 + threadIdx.x;
    if (e < E) {
        int t = tgt[e];
        int p = atomicAdd(&cursor[t], 1);
        csr[p] = src[e];
    }
}

// one wave (64 lanes) per node: sum x[src] rows (float2/lane), /max(deg,1), +residual
__global__ void agg_combine_kernel(const float* __restrict__ hin,
                                   const int* __restrict__ offsets,
                                   const int* __restrict__ csr,
                                   float* __restrict__ out, int N) {
    int wid = (blockIdx.x * blockDim.x + threadIdx.x) >> 6;
    int lane = threadIdx.x & 63;
    if (wid >= N) return;
    int s0 = offsets[wid], s1 = offsets[wid + 1];
    int nedge = s1 - s0;
    const float2* h2 = (const float2*)hin;
    float2 acc = make_float2(0.f, 0.f);
    for (int base = 0; base < nedge; base += 64) {
        int rem = nedge - base;
        int cnt = rem < 64 ? rem : 64;
        int my = (lane < cnt) ? csr[s0 + base + lane] : 0;  // coalesced index load
        for (int t = 0; t < cnt; ++t) {
            int s = __shfl(my, t, 64);                      // broadcast, no mem dep
            float2 v = h2[s * 64 + lane];                   // coalesced 512B row
            acc.x += v.x; acc.y += v.y;
        }
    }
    float inv = 1.0f / fmaxf((float)nedge, 1.0f);
    float2 self = h2[wid * 64 + lane];
    float2 o;
    o.x = self.x + acc.x * inv;
    o.y = self.y + acc.y * inv;
    ((float2*)out)[wid * 64 + lane] = o;
}

// C[M,128] = relu?(A[M,128] @ W[128,128] + b)
// 128x128 block tile, K-chunk 64 in LDS (32KB A + 32KB W), 8x8 micro-tile.
__global__ __launch_bounds__(256, 2)
void gemm_relu128(const float* __restrict__ A, const float* __restrict__ W,
                  const float* __restrict__ bias, float* __restrict__ out,
                  int M, int relu) {
    __shared__ float As[128 * 64];   // [r][k] chunk
    __shared__ float Ws[64 * 128];   // [k][c] chunk
    const int tid = threadIdx.x;
    const int row0 = blockIdx.x * 128;
    const int c0 = (tid & 15) * 8;
    const int r0 = (tid >> 4) * 8;
    float acc[8][8];
#pragma unroll
    for (int i = 0; i < 8; ++i)
#pragma unroll
        for (int j = 0; j < 8; ++j) acc[i][j] = 0.f;

    for (int k0 = 0; k0 < 128; k0 += 64) {
        // stage A chunk: 128 rows x 64 k  (2048 float4, 8 per thread)
#pragma unroll
        for (int i = 0; i < 8; ++i) {
            int f = tid + i * 256;
            int r = f >> 4;        // 16 float4 per row
            int c4 = f & 15;
            float4 v = make_float4(0.f, 0.f, 0.f, 0.f);
            int gr = row0 + r;
            if (gr < M) v = *(const float4*)&A[gr * 128 + k0 + c4 * 4];
            *(float4*)&As[r * 64 + c4 * 4] = v;
        }
        // stage W chunk: 64 k x 128 c
#pragma unroll
        for (int i = 0; i < 8; ++i) {
            int f = tid + i * 256;
            int kk = f >> 5;       // 32 float4 per row
            int c4 = f & 31;
            *(float4*)&Ws[kk * 128 + c4 * 4] = *(const float4*)&W[(k0 + kk) * 128 + c4 * 4];
        }
        __syncthreads();

        for (int kk = 0; kk < 64; kk += 4) {
            float4 av[8];
#pragma unroll
            for (int i = 0; i < 8; ++i) av[i] = *(const float4*)&As[(r0 + i) * 64 + kk];
#pragma unroll
            for (int u = 0; u < 4; ++u) {
                float4 w0 = *(const float4*)&Ws[(kk + u) * 128 + c0];
                float4 w1 = *(const float4*)&Ws[(kk + u) * 128 + c0 + 4];
#pragma unroll
                for (int i = 0; i < 8; ++i) {
                    float a = (&av[i].x)[u];
                    acc[i][0] += a * w0.x; acc[i][1] += a * w0.y;
                    acc[i][2] += a * w0.z; acc[i][3] += a * w0.w;
                    acc[i][4] += a * w1.x; acc[i][5] += a * w1.y;
                    acc[i][6] += a * w1.z; acc[i][7] += a * w1.w;
                }
            }
        }
        __syncthreads();
    }

    float4 b0 = *(const float4*)&bias[c0];
    float4 b1 = *(const float4*)&bias[c0 + 4];
#pragma unroll
    for (int i = 0; i < 8; ++i) {
        int gr = row0 + r0 + i;
        if (gr < M) {
            float o[8];
            o[0] = acc[i][0] + b0.x; o[1] = acc[i][1] + b0.y;
            o[2] = acc[i][2] + b0.z; o[3] = acc[i][3] + b0.w;
            o[4] = acc[i][4] + b1.x; o[5] = acc[i][5] + b1.y;
            o[6] = acc[i][6] + b1.z; o[7] = acc[i][7] + b1.w;
            if (relu) {
#pragma unroll
                for (int j = 0; j < 8; ++j) o[j] = fmaxf(o[j], 0.f);
            }
            *(float4*)&out[gr * 128 + c0]     = make_float4(o[0], o[1], o[2], o[3]);
            *(float4*)&out[gr * 128 + c0 + 4] = make_float4(o[4], o[5], o[6], o[7]);
        }
    }
}

// out[N,5] = h[N,128] @ Wp[128,5] + bp  — one wave per node, shuffle reduce
__global__ void proj_kernel(const float* __restrict__ h, const float* __restrict__ Wp,
                            const float* __restrict__ bp, float* __restrict__ out, int N) {
    int wid = (blockIdx.x * blockDim.x + threadIdx.x) >> 6;
    int lane = threadIdx.x & 63;
    if (wid >= N) return;
    float2 v = ((const float2*)h)[wid * 64 + lane];
    float p[5];
#pragma unroll
    for (int j = 0; j < 5; ++j)
        p[j] = v.x * Wp[(2 * lane) * 5 + j] + v.y * Wp[(2 * lane + 1) * 5 + j];
#pragma unroll
    for (int m = 32; m >= 1; m >>= 1) {
#pragma unroll
        for (int j = 0; j < 5; ++j) p[j] += __shfl_xor(p[j], m, 64);
    }
    if (lane == 0) {
#pragma unroll
        for (int j = 0; j < 5; ++j) out[wid * 5 + j] = p[j] + bp[j];
    }
}

extern "C" void kernel_launch(void* const* d_in, const int* in_sizes, int n_in,
                              void* d_out, int out_size, void* d_ws, size_t ws_size,
                              hipStream_t stream) {
    const float* x     = (const float*)d_in[0];
    const int*   edges = (const int*)d_in[1];
    const float* W1    = (const float*)d_in[2];
    const float* b1    = (const float*)d_in[3];
    const float* W2    = (const float*)d_in[4];
    const float* b2    = (const float*)d_in[5];
    const float* Wp    = (const float*)d_in[6];
    const float* bp    = (const float*)d_in[7];
    float* out = (float*)d_out;

    const int N = in_sizes[0] / 128;   // 100000
    const int E = in_sizes[1] / 2;     // 1600000
    const int* src = edges;
    const int* tgt = edges + E;

    // workspace carve-up (256B aligned)
    char* ws = (char*)d_ws;
    size_t off = 0;
    auto alloc = [&](size_t bytes) {
        char* p = ws + off;
        off = (off + bytes + 255) & ~(size_t)255;
        return p;
    };
    int*   deg       = (int*)alloc((size_t)N * 4);
    int*   offsets   = (int*)alloc((size_t)(N + 1) * 4);
    int*   cursor    = (int*)alloc((size_t)N * 4);
    int*   blockSums = (int*)alloc(1024 * 4);
    int*   csr       = (int*)alloc((size_t)E * 4);
    float* bufA      = (float*)alloc((size_t)N * 128 * 4);
    float* bufB      = (float*)alloc((size_t)N * 128 * 4);
    (void)ws_size;

    const int nb = (N + 1023) / 1024;

    hipMemsetAsync(deg, 0, (size_t)N * 4, stream);
    degree_kernel<<<(E + 255) / 256, 256, 0, stream>>>(tgt, deg, E);
    scan1_kernel<<<nb, 256, 0, stream>>>(deg, offsets, blockSums, N);
    scan2_kernel<<<1, 64, 0, stream>>>(blockSums, nb, offsets, N);
    scan3_kernel<<<nb, 256, 0, stream>>>(offsets, cursor, blockSums, N);
    fill_csr_kernel<<<(E + 255) / 256, 256, 0, stream>>>(src, tgt, cursor, csr, E);

    const int aggBlocks  = (N + 3) / 4;        // 4 waves (nodes) per 256-thr block
    const int gemmBlocks = (N + 127) / 128;

    // layer 1
    agg_combine_kernel<<<aggBlocks, 256, 0, stream>>>(x, offsets, csr, bufA, N);
    gemm_relu128<<<gemmBlocks, 256, 0, stream>>>(bufA, W1, b1, bufB, N, 1);
    // layer 2
    agg_combine_kernel<<<aggBlocks, 256, 0, stream>>>(bufB, offsets, csr, bufA, N);
    gemm_relu128<<<gemmBlocks, 256, 0, stream>>>(bufA, W2, b2, bufB, N, 1);
    // projection
    proj_kernel<<<aggBlocks, 256, 0, stream>>>(bufB, Wp, bp, out, N);
}

// Round 2
// 574.258 us; speedup vs baseline: 1.2071x; 1.2071x over previous
//
#include <hip/hip_runtime.h>

typedef unsigned int uint32;
typedef unsigned short ushort16;

// ---------------------------------------------------------------------------
// GNN: h1 = relu((x + mean_agg(x)) @ W1 + b1)
//      h2 = relu((h1 + mean_agg(h1)) @ W2 + b2)
//      out = h2 @ Wp + bp
// R2: bf16 gather operand (halves agg HBM traffic), 4-edges-per-wave gather,
//     projection fused into layer-2 GEMM epilogue.
// ---------------------------------------------------------------------------

__device__ __forceinline__ ushort16 f2bf(float f) {
    uint32 u = __float_as_uint(f);
    u += 0x7fffu + ((u >> 16) & 1u);       // round-to-nearest-even
    return (ushort16)(u >> 16);
}
__device__ __forceinline__ float bfhi(uint32 u) { return __uint_as_float(u & 0xffff0000u); }
__device__ __forceinline__ float bflo(uint32 u) { return __uint_as_float(u << 16); }

__global__ void cvt_bf16_kernel(const float* __restrict__ in, ushort16* __restrict__ out, int n8) {
    int i = blockIdx.x * 256 + threadIdx.x;
    if (i >= n8) return;
    const float4* p = (const float4*)in + 2 * (size_t)i;
    float4 a = p[0], b = p[1];
    uint4 o;
    o.x = (uint32)f2bf(a.x) | ((uint32)f2bf(a.y) << 16);
    o.y = (uint32)f2bf(a.z) | ((uint32)f2bf(a.w) << 16);
    o.z = (uint32)f2bf(b.x) | ((uint32)f2bf(b.y) << 16);
    o.w = (uint32)f2bf(b.z) | ((uint32)f2bf(b.w) << 16);
    ((uint4*)out)[i] = o;
}

__global__ void degree_kernel(const int* __restrict__ tgt, int* __restrict__ deg, int E) {
    int e = blockIdx.x * 256 + threadIdx.x;
    if (e < E) atomicAdd(&deg[tgt[e]], 1);
}

// block scans 1024 elements (256 thr x 4); writes exclusive prefix + block sum
__global__ void scan1_kernel(const int* __restrict__ deg, int* __restrict__ excl,
                             int* __restrict__ blockSums, int N) {
    __shared__ int sd[256];
    int tid = threadIdx.x;
    int base = blockIdx.x * 1024 + tid * 4;
    int v0 = 0, v1 = 0, v2 = 0, v3 = 0;
    if (base + 3 < N) {
        int4 t = *(const int4*)&deg[base];
        v0 = t.x; v1 = t.y; v2 = t.z; v3 = t.w;
    } else {
        if (base     < N) v0 = deg[base];
        if (base + 1 < N) v1 = deg[base + 1];
        if (base + 2 < N) v2 = deg[base + 2];
    }
    int sum = v0 + v1 + v2 + v3;
    sd[tid] = sum;
    __syncthreads();
    for (int o = 1; o < 256; o <<= 1) {
        int t = (tid >= o) ? sd[tid - o] : 0;
        __syncthreads();
        sd[tid] += t;
        __syncthreads();
    }
    int run = sd[tid] - sum;  // exclusive within block
    if (base     < N) excl[base]     = run; run += v0;
    if (base + 1 < N) excl[base + 1] = run; run += v1;
    if (base + 2 < N) excl[base + 2] = run; run += v2;
    if (base + 3 < N) excl[base + 3] = run;
    if (tid == 255) blockSums[blockIdx.x] = sd[255];
}

__global__ void scan2_kernel(int* blockSums, int nb, int* offsets, int N) {
    if (threadIdx.x == 0 && blockIdx.x == 0) {
        int run = 0;
        for (int b = 0; b < nb; ++b) { int t = blockSums[b]; blockSums[b] = run; run += t; }
        offsets[N] = run;
    }
}

__global__ void scan3_kernel(int* __restrict__ offsets, int* __restrict__ cursor,
                             const int* __restrict__ blockSums, int N) {
    int tid = threadIdx.x;
    int base = blockIdx.x * 1024 + tid * 4;
    int bs = blockSums[blockIdx.x];
#pragma unroll
    for (int i = 0; i < 4; ++i) {
        int idx = base + i;
        if (idx < N) { int o = offsets[idx] + bs; offsets[idx] = o; cursor[idx] = o; }
    }
}

__global__ void fill_csr_kernel(const int* __restrict__ src, const int* __restrict__ tgt,
                                int* __restrict__ cursor, int* __restrict__ csr, int E) {
    int e = blockIdx.x * 256 + threadIdx.x;
    if (e < E) {
        int t = tgt[e];
        int p = atomicAdd(&cursor[t], 1);
        csr[p] = src[e];
    }
}

// one wave per node; 4 edges in flight (lane-group g of 16 lanes loads one
// 256B bf16 row as uint4); residual read fp32; output fp32 combined.
__global__ __launch_bounds__(256, 4)
void agg_combine_bf16_kernel(const float* __restrict__ hres, const ushort16* __restrict__ hb,
                             const int* __restrict__ offsets, const int* __restrict__ csr,
                             float* __restrict__ out, int N) {
    int wid = (blockIdx.x * 256 + threadIdx.x) >> 6;
    int lane = threadIdx.x & 63;
    if (wid >= N) return;
    int g = lane >> 4, sl = lane & 15;
    int s0 = offsets[wid];
    int deg = offsets[wid + 1] - s0;
    float acc[8];
#pragma unroll
    for (int j = 0; j < 8; ++j) acc[j] = 0.f;

    for (int base = 0; base < deg; base += 4) {
        int e = base + g;
        if (e < deg) {
            int s = csr[s0 + e];                       // broadcast within 16-lane group
            uint4 v = *(const uint4*)(hb + (size_t)s * 128 + sl * 8);  // 256B row / group
            acc[0] += bflo(v.x); acc[1] += bfhi(v.x);
            acc[2] += bflo(v.y); acc[3] += bfhi(v.y);
            acc[4] += bflo(v.z); acc[5] += bfhi(v.z);
            acc[6] += bflo(v.w); acc[7] += bfhi(v.w);
        }
    }
    // reduce the 4 lane-groups (each holds partials for channels sl*8..sl*8+7)
#pragma unroll
    for (int j = 0; j < 8; ++j) {
        acc[j] += __shfl_xor(acc[j], 16, 64);
        acc[j] += __shfl_xor(acc[j], 32, 64);
    }
    float inv = 1.f / fmaxf((float)deg, 1.f);
    // lane writes float2 index sl*4+g -> channels sl*8+2g, sl*8+2g+1 = acc[2g],acc[2g+1]
    float ax = (g == 0) ? acc[0] : (g == 1) ? acc[2] : (g == 2) ? acc[4] : acc[6];
    float ay = (g == 0) ? acc[1] : (g == 1) ? acc[3] : (g == 2) ? acc[5] : acc[7];
    int fi = sl * 4 + g;
    float2 self = ((const float2*)hres)[(size_t)wid * 64 + fi];
    float2 o;
    o.x = self.x + ax * inv;
    o.y = self.y + ay * inv;
    ((float2*)out)[(size_t)wid * 64 + fi] = o;
}

// C[M,128] = relu(A[M,128] @ W[128,128] + b)
// outP==null: write fp32 h to outF (+ bf16 copy to outB if set)
// outP!=null: fuse out = h @ Wp + bp  (shfl-reduce across 16 lanes per row)
__global__ __launch_bounds__(256, 2)
void gemm_kernel(const float* __restrict__ A, const float* __restrict__ W,
                 const float* __restrict__ bias, int M,
                 float* __restrict__ outF, ushort16* __restrict__ outB,
                 const float* __restrict__ Wp, const float* __restrict__ bp,
                 float* __restrict__ outP) {
    __shared__ float As[128 * 64];
    __shared__ float Ws[64 * 128];
    const int tid = threadIdx.x;
    const int row0 = blockIdx.x * 128;
    const int c0 = (tid & 15) * 8;
    const int r0 = (tid >> 4) * 8;
    float acc[8][8];
#pragma unroll
    for (int i = 0; i < 8; ++i)
#pragma unroll
        for (int j = 0; j < 8; ++j) acc[i][j] = 0.f;

    for (int k0 = 0; k0 < 128; k0 += 64) {
#pragma unroll
        for (int i = 0; i < 8; ++i) {
            int f = tid + i * 256;
            int r = f >> 4;
            int c4 = f & 15;
            float4 v = make_float4(0.f, 0.f, 0.f, 0.f);
            int gr = row0 + r;
            if (gr < M) v = *(const float4*)&A[(size_t)gr * 128 + k0 + c4 * 4];
            *(float4*)&As[r * 64 + c4 * 4] = v;
        }
#pragma unroll
        for (int i = 0; i < 8; ++i) {
            int f = tid + i * 256;
            int kk = f >> 5;
            int c4 = f & 31;
            *(float4*)&Ws[kk * 128 + c4 * 4] = *(const float4*)&W[(size_t)(k0 + kk) * 128 + c4 * 4];
        }
        __syncthreads();

        for (int kk = 0; kk < 64; kk += 4) {
            float4 av[8];
#pragma unroll
            for (int i = 0; i < 8; ++i) av[i] = *(const float4*)&As[(r0 + i) * 64 + kk];
#pragma unroll
            for (int u = 0; u < 4; ++u) {
                float4 w0 = *(const float4*)&Ws[(kk + u) * 128 + c0];
                float4 w1 = *(const float4*)&Ws[(kk + u) * 128 + c0 + 4];
#pragma unroll
                for (int i = 0; i < 8; ++i) {
                    float a = (&av[i].x)[u];
                    acc[i][0] += a * w0.x; acc[i][1] += a * w0.y;
                    acc[i][2] += a * w0.z; acc[i][3] += a * w0.w;
                    acc[i][4] += a * w1.x; acc[i][5] += a * w1.y;
                    acc[i][6] += a * w1.z; acc[i][7] += a * w1.w;
                }
            }
        }
        __syncthreads();
    }

    float4 b0 = *(const float4*)&bias[c0];
    float4 b1 = *(const float4*)&bias[c0 + 4];

    float wp[8][5];
    if (outP) {
#pragma unroll
        for (int c = 0; c < 8; ++c)
#pragma unroll
            for (int j = 0; j < 5; ++j) wp[c][j] = Wp[(c0 + c) * 5 + j];
    }

#pragma unroll
    for (int i = 0; i < 8; ++i) {
        int gr = row0 + r0 + i;
        bool valid = gr < M;
        float o[8];
        o[0] = fmaxf(acc[i][0] + b0.x, 0.f); o[1] = fmaxf(acc[i][1] + b0.y, 0.f);
        o[2] = fmaxf(acc[i][2] + b0.z, 0.f); o[3] = fmaxf(acc[i][3] + b0.w, 0.f);
        o[4] = fmaxf(acc[i][4] + b1.x, 0.f); o[5] = fmaxf(acc[i][5] + b1.y, 0.f);
        o[6] = fmaxf(acc[i][6] + b1.z, 0.f); o[7] = fmaxf(acc[i][7] + b1.w, 0.f);
        if (outP) {
            float p[5];
#pragma unroll
            for (int j = 0; j < 5; ++j) {
                p[j] = o[0] * wp[0][j] + o[1] * wp[1][j] + o[2] * wp[2][j] + o[3] * wp[3][j]
                     + o[4] * wp[4][j] + o[5] * wp[5][j] + o[6] * wp[6][j] + o[7] * wp[7][j];
            }
#pragma unroll
            for (int m = 1; m <= 8; m <<= 1) {
#pragma unroll
                for (int j = 0; j < 5; ++j) p[j] += __shfl_xor(p[j], m, 64);
            }
            if (valid && (tid & 15) == 0) {
#pragma unroll
                for (int j = 0; j < 5; ++j) outP[(size_t)gr * 5 + j] = p[j] + bp[j];
            }
        } else if (valid) {
            *(float4*)&outF[(size_t)gr * 128 + c0]     = make_float4(o[0], o[1], o[2], o[3]);
            *(float4*)&outF[(size_t)gr * 128 + c0 + 4] = make_float4(o[4], o[5], o[6], o[7]);
            if (outB) {
                uint4 pk;
                pk.x = (uint32)f2bf(o[0]) | ((uint32)f2bf(o[1]) << 16);
                pk.y = (uint32)f2bf(o[2]) | ((uint32)f2bf(o[3]) << 16);
                pk.z = (uint32)f2bf(o[4]) | ((uint32)f2bf(o[5]) << 16);
                pk.w = (uint32)f2bf(o[6]) | ((uint32)f2bf(o[7]) << 16);
                *(uint4*)(outB + (size_t)gr * 128 + c0) = pk;
            }
        }
    }
}

extern "C" void kernel_launch(void* const* d_in, const int* in_sizes, int n_in,
                              void* d_out, int out_size, void* d_ws, size_t ws_size,
                              hipStream_t stream) {
    const float* x     = (const float*)d_in[0];
    const int*   edges = (const int*)d_in[1];
    const float* W1    = (const float*)d_in[2];
    const float* b1    = (const float*)d_in[3];
    const float* W2    = (const float*)d_in[4];
    const float* b2    = (const float*)d_in[5];
    const float* Wp    = (const float*)d_in[6];
    const float* bp    = (const float*)d_in[7];
    float* out = (float*)d_out;

    const int N = in_sizes[0] / 128;   // 100000
    const int E = in_sizes[1] / 2;     // 1600000
    const int* src = edges;
    const int* tgt = edges + E;

    char* ws = (char*)d_ws;
    size_t off = 0;
    auto alloc = [&](size_t bytes) {
        char* p = ws + off;
        off = (off + bytes + 255) & ~(size_t)255;
        return p;
    };
    int*      deg       = (int*)alloc((size_t)N * 4);
    int*      offsets   = (int*)alloc((size_t)(N + 1) * 4);
    int*      cursor    = (int*)alloc((size_t)N * 4);
    int*      blockSums = (int*)alloc(1024 * 4);
    int*      csr       = (int*)alloc((size_t)E * 4);
    ushort16* xb        = (ushort16*)alloc((size_t)N * 128 * 2);
    ushort16* hb1       = (ushort16*)alloc((size_t)N * 128 * 2);
    float*    bufA      = (float*)alloc((size_t)N * 128 * 4);   // combined (GEMM input)
    float*    bufB      = (float*)alloc((size_t)N * 128 * 4);   // h1 fp32
    (void)ws_size;

    const int nb = (N + 1023) / 1024;
    const int n8 = N * 16;  // N*128/8

    hipMemsetAsync(deg, 0, (size_t)N * 4, stream);
    cvt_bf16_kernel<<<(n8 + 255) / 256, 256, 0, stream>>>(x, xb, n8);
    degree_kernel<<<(E + 255) / 256, 256, 0, stream>>>(tgt, deg, E);
    scan1_kernel<<<nb, 256, 0, stream>>>(deg, offsets, blockSums, N);
    scan2_kernel<<<1, 64, 0, stream>>>(blockSums, nb, offsets, N);
    scan3_kernel<<<nb, 256, 0, stream>>>(offsets, cursor, blockSums, N);
    fill_csr_kernel<<<(E + 255) / 256, 256, 0, stream>>>(src, tgt, cursor, csr, E);

    const int aggBlocks  = (N + 3) / 4;
    const int gemmBlocks = (N + 127) / 128;

    // layer 1
    agg_combine_bf16_kernel<<<aggBlocks, 256, 0, stream>>>(x, xb, offsets, csr, bufA, N);
    gemm_kernel<<<gemmBlocks, 256, 0, stream>>>(bufA, W1, b1, N, bufB, hb1,
                                                nullptr, nullptr, nullptr);
    // layer 2
    agg_combine_bf16_kernel<<<aggBlocks, 256, 0, stream>>>(bufB, hb1, offsets, csr, bufA, N);
    // layer 2 GEMM with fused projection -> out
    gemm_kernel<<<gemmBlocks, 256, 0, stream>>>(bufA, W2, b2, N, nullptr, nullptr,
                                                Wp, bp, out);
}

// Round 3
// 491.505 us; speedup vs baseline: 1.4103x; 1.1684x over previous
//
#include <hip/hip_runtime.h>

typedef unsigned int uint32;
typedef unsigned short ushort16;

// ---------------------------------------------------------------------------
// GNN: h1 = relu((x + mean_agg(x)) @ W1 + b1)
//      h2 = relu((h1 + mean_agg(h1)) @ W2 + b2)
//      out = h2 @ Wp + bp
// R3: CSR build restructured — single atomic rank pass (deg+cursor merged,
//     4-deep atomic ILP), atomic-free scatter fill. bf16 gather unchanged.
// ---------------------------------------------------------------------------

__device__ __forceinline__ ushort16 f2bf(float f) {
    uint32 u = __float_as_uint(f);
    u += 0x7fffu + ((u >> 16) & 1u);       // round-to-nearest-even
    return (ushort16)(u >> 16);
}
__device__ __forceinline__ float bfhi(uint32 u) { return __uint_as_float(u & 0xffff0000u); }
__device__ __forceinline__ float bflo(uint32 u) { return __uint_as_float(u << 16); }

__global__ void cvt_bf16_kernel(const float* __restrict__ in, ushort16* __restrict__ out, int n8) {
    int i = blockIdx.x * 256 + threadIdx.x;
    if (i >= n8) return;
    const float4* p = (const float4*)in + 2 * (size_t)i;
    float4 a = p[0], b = p[1];
    uint4 o;
    o.x = (uint32)f2bf(a.x) | ((uint32)f2bf(a.y) << 16);
    o.y = (uint32)f2bf(a.z) | ((uint32)f2bf(a.w) << 16);
    o.z = (uint32)f2bf(b.x) | ((uint32)f2bf(b.y) << 16);
    o.w = (uint32)f2bf(b.z) | ((uint32)f2bf(b.w) << 16);
    ((uint4*)out)[i] = o;
}

// rank[e] = position of edge e within its target's bucket; deg[t] = final count.
// 4 edges/thread: 4 independent atomic returns in flight per lane.
__global__ void rank_kernel(const int* __restrict__ tgt, int* __restrict__ deg,
                            int* __restrict__ rank, int E4, int tail, int E) {
    int i = blockIdx.x * 256 + threadIdx.x;
    if (i < E4) {
        int4 t = ((const int4*)tgt)[i];
        int4 r;
        r.x = atomicAdd(&deg[t.x], 1);
        r.y = atomicAdd(&deg[t.y], 1);
        r.z = atomicAdd(&deg[t.z], 1);
        r.w = atomicAdd(&deg[t.w], 1);
        ((int4*)rank)[i] = r;
    } else if (i == E4 && tail) {
        for (int e = E4 * 4; e < E; ++e) rank[e] = atomicAdd(&deg[tgt[e]], 1);
    }
}

// block scans 1024 elements (256 thr x 4); writes exclusive prefix + block sum
__global__ void scan1_kernel(const int* __restrict__ deg, int* __restrict__ excl,
                             int* __restrict__ blockSums, int N) {
    __shared__ int sd[256];
    int tid = threadIdx.x;
    int base = blockIdx.x * 1024 + tid * 4;
    int v0 = 0, v1 = 0, v2 = 0, v3 = 0;
    if (base + 3 < N) {
        int4 t = *(const int4*)&deg[base];
        v0 = t.x; v1 = t.y; v2 = t.z; v3 = t.w;
    } else {
        if (base     < N) v0 = deg[base];
        if (base + 1 < N) v1 = deg[base + 1];
        if (base + 2 < N) v2 = deg[base + 2];
    }
    int sum = v0 + v1 + v2 + v3;
    sd[tid] = sum;
    __syncthreads();
    for (int o = 1; o < 256; o <<= 1) {
        int t = (tid >= o) ? sd[tid - o] : 0;
        __syncthreads();
        sd[tid] += t;
        __syncthreads();
    }
    int run = sd[tid] - sum;  // exclusive within block
    if (base     < N) excl[base]     = run; run += v0;
    if (base + 1 < N) excl[base + 1] = run; run += v1;
    if (base + 2 < N) excl[base + 2] = run; run += v2;
    if (base + 3 < N) excl[base + 3] = run;
    if (tid == 255) blockSums[blockIdx.x] = sd[255];
}

__global__ void scan2_kernel(int* blockSums, int nb, int* offsets, int N) {
    if (threadIdx.x == 0 && blockIdx.x == 0) {
        int run = 0;
        for (int b = 0; b < nb; ++b) { int t = blockSums[b]; blockSums[b] = run; run += t; }
        offsets[N] = run;
    }
}

__global__ void scan3_kernel(int* __restrict__ offsets, const int* __restrict__ blockSums, int N) {
    int tid = threadIdx.x;
    int base = blockIdx.x * 1024 + tid * 4;
    int bs = blockSums[blockIdx.x];
#pragma unroll
    for (int i = 0; i < 4; ++i) {
        int idx = base + i;
        if (idx < N) offsets[idx] += bs;
    }
}

// atomic-free scatter: csr[offsets[t] + rank[e]] = src[e]
__global__ void fill_kernel(const int* __restrict__ src, const int* __restrict__ tgt,
                            const int* __restrict__ rank, const int* __restrict__ offsets,
                            int* __restrict__ csr, int E4, int tail, int E) {
    int i = blockIdx.x * 256 + threadIdx.x;
    if (i < E4) {
        int4 t = ((const int4*)tgt)[i];
        int4 r = ((const int4*)rank)[i];
        int4 s = ((const int4*)src)[i];
        csr[offsets[t.x] + r.x] = s.x;
        csr[offsets[t.y] + r.y] = s.y;
        csr[offsets[t.z] + r.z] = s.z;
        csr[offsets[t.w] + r.w] = s.w;
    } else if (i == E4 && tail) {
        for (int e = E4 * 4; e < E; ++e) csr[offsets[tgt[e]] + rank[e]] = src[e];
    }
}

// one wave per node; 4 edges in flight (lane-group g of 16 lanes loads one
// 256B bf16 row as uint4); residual read fp32; output fp32 combined.
__global__ __launch_bounds__(256, 4)
void agg_combine_bf16_kernel(const float* __restrict__ hres, const ushort16* __restrict__ hb,
                             const int* __restrict__ offsets, const int* __restrict__ csr,
                             float* __restrict__ out, int N) {
    int wid = (blockIdx.x * 256 + threadIdx.x) >> 6;
    int lane = threadIdx.x & 63;
    if (wid >= N) return;
    int g = lane >> 4, sl = lane & 15;
    int s0 = offsets[wid];
    int deg = offsets[wid + 1] - s0;
    float acc[8];
#pragma unroll
    for (int j = 0; j < 8; ++j) acc[j] = 0.f;

    for (int base = 0; base < deg; base += 4) {
        int e = base + g;
        if (e < deg) {
            int s = csr[s0 + e];                       // broadcast within 16-lane group
            uint4 v = *(const uint4*)(hb + (size_t)s * 128 + sl * 8);  // 256B row / group
            acc[0] += bflo(v.x); acc[1] += bfhi(v.x);
            acc[2] += bflo(v.y); acc[3] += bfhi(v.y);
            acc[4] += bflo(v.z); acc[5] += bfhi(v.z);
            acc[6] += bflo(v.w); acc[7] += bfhi(v.w);
        }
    }
    // reduce the 4 lane-groups (each holds partials for channels sl*8..sl*8+7)
#pragma unroll
    for (int j = 0; j < 8; ++j) {
        acc[j] += __shfl_xor(acc[j], 16, 64);
        acc[j] += __shfl_xor(acc[j], 32, 64);
    }
    float inv = 1.f / fmaxf((float)deg, 1.f);
    // lane writes float2 index sl*4+g -> channels sl*8+2g, sl*8+2g+1 = acc[2g],acc[2g+1]
    float ax = (g == 0) ? acc[0] : (g == 1) ? acc[2] : (g == 2) ? acc[4] : acc[6];
    float ay = (g == 0) ? acc[1] : (g == 1) ? acc[3] : (g == 2) ? acc[5] : acc[7];
    int fi = sl * 4 + g;
    float2 self = ((const float2*)hres)[(size_t)wid * 64 + fi];
    float2 o;
    o.x = self.x + ax * inv;
    o.y = self.y + ay * inv;
    ((float2*)out)[(size_t)wid * 64 + fi] = o;
}

// C[M,128] = relu(A[M,128] @ W[128,128] + b)
// outP==null: write fp32 h to outF (+ bf16 copy to outB if set)
// outP!=null: fuse out = h @ Wp + bp  (shfl-reduce across 16 lanes per row)
__global__ __launch_bounds__(256, 2)
void gemm_kernel(const float* __restrict__ A, const float* __restrict__ W,
                 const float* __restrict__ bias, int M,
                 float* __restrict__ outF, ushort16* __restrict__ outB,
                 const float* __restrict__ Wp, const float* __restrict__ bp,
                 float* __restrict__ outP) {
    __shared__ float As[128 * 64];
    __shared__ float Ws[64 * 128];
    const int tid = threadIdx.x;
    const int row0 = blockIdx.x * 128;
    const int c0 = (tid & 15) * 8;
    const int r0 = (tid >> 4) * 8;
    float acc[8][8];
#pragma unroll
    for (int i = 0; i < 8; ++i)
#pragma unroll
        for (int j = 0; j < 8; ++j) acc[i][j] = 0.f;

    for (int k0 = 0; k0 < 128; k0 += 64) {
#pragma unroll
        for (int i = 0; i < 8; ++i) {
            int f = tid + i * 256;
            int r = f >> 4;
            int c4 = f & 15;
            float4 v = make_float4(0.f, 0.f, 0.f, 0.f);
            int gr = row0 + r;
            if (gr < M) v = *(const float4*)&A[(size_t)gr * 128 + k0 + c4 * 4];
            *(float4*)&As[r * 64 + c4 * 4] = v;
        }
#pragma unroll
        for (int i = 0; i < 8; ++i) {
            int f = tid + i * 256;
            int kk = f >> 5;
            int c4 = f & 31;
            *(float4*)&Ws[kk * 128 + c4 * 4] = *(const float4*)&W[(size_t)(k0 + kk) * 128 + c4 * 4];
        }
        __syncthreads();

        for (int kk = 0; kk < 64; kk += 4) {
            float4 av[8];
#pragma unroll
            for (int i = 0; i < 8; ++i) av[i] = *(const float4*)&As[(r0 + i) * 64 + kk];
#pragma unroll
            for (int u = 0; u < 4; ++u) {
                float4 w0 = *(const float4*)&Ws[(kk + u) * 128 + c0];
                float4 w1 = *(const float4*)&Ws[(kk + u) * 128 + c0 + 4];
#pragma unroll
                for (int i = 0; i < 8; ++i) {
                    float a = (&av[i].x)[u];
                    acc[i][0] += a * w0.x; acc[i][1] += a * w0.y;
                    acc[i][2] += a * w0.z; acc[i][3] += a * w0.w;
                    acc[i][4] += a * w1.x; acc[i][5] += a * w1.y;
                    acc[i][6] += a * w1.z; acc[i][7] += a * w1.w;
                }
            }
        }
        __syncthreads();
    }

    float4 b0 = *(const float4*)&bias[c0];
    float4 b1 = *(const float4*)&bias[c0 + 4];

    float wp[8][5];
    if (outP) {
#pragma unroll
        for (int c = 0; c < 8; ++c)
#pragma unroll
            for (int j = 0; j < 5; ++j) wp[c][j] = Wp[(c0 + c) * 5 + j];
    }

#pragma unroll
    for (int i = 0; i < 8; ++i) {
        int gr = row0 + r0 + i;
        bool valid = gr < M;
        float o[8];
        o[0] = fmaxf(acc[i][0] + b0.x, 0.f); o[1] = fmaxf(acc[i][1] + b0.y, 0.f);
        o[2] = fmaxf(acc[i][2] + b0.z, 0.f); o[3] = fmaxf(acc[i][3] + b0.w, 0.f);
        o[4] = fmaxf(acc[i][4] + b1.x, 0.f); o[5] = fmaxf(acc[i][5] + b1.y, 0.f);
        o[6] = fmaxf(acc[i][6] + b1.z, 0.f); o[7] = fmaxf(acc[i][7] + b1.w, 0.f);
        if (outP) {
            float p[5];
#pragma unroll
            for (int j = 0; j < 5; ++j) {
                p[j] = o[0] * wp[0][j] + o[1] * wp[1][j] + o[2] * wp[2][j] + o[3] * wp[3][j]
                     + o[4] * wp[4][j] + o[5] * wp[5][j] + o[6] * wp[6][j] + o[7] * wp[7][j];
            }
#pragma unroll
            for (int m = 1; m <= 8; m <<= 1) {
#pragma unroll
                for (int j = 0; j < 5; ++j) p[j] += __shfl_xor(p[j], m, 64);
            }
            if (valid && (tid & 15) == 0) {
#pragma unroll
                for (int j = 0; j < 5; ++j) outP[(size_t)gr * 5 + j] = p[j] + bp[j];
            }
        } else if (valid) {
            *(float4*)&outF[(size_t)gr * 128 + c0]     = make_float4(o[0], o[1], o[2], o[3]);
            *(float4*)&outF[(size_t)gr * 128 + c0 + 4] = make_float4(o[4], o[5], o[6], o[7]);
            if (outB) {
                uint4 pk;
                pk.x = (uint32)f2bf(o[0]) | ((uint32)f2bf(o[1]) << 16);
                pk.y = (uint32)f2bf(o[2]) | ((uint32)f2bf(o[3]) << 16);
                pk.z = (uint32)f2bf(o[4]) | ((uint32)f2bf(o[5]) << 16);
                pk.w = (uint32)f2bf(o[6]) | ((uint32)f2bf(o[7]) << 16);
                *(uint4*)(outB + (size_t)gr * 128 + c0) = pk;
            }
        }
    }
}

extern "C" void kernel_launch(void* const* d_in, const int* in_sizes, int n_in,
                              void* d_out, int out_size, void* d_ws, size_t ws_size,
                              hipStream_t stream) {
    const float* x     = (const float*)d_in[0];
    const int*   edges = (const int*)d_in[1];
    const float* W1    = (const float*)d_in[2];
    const float* b1    = (const float*)d_in[3];
    const float* W2    = (const float*)d_in[4];
    const float* b2    = (const float*)d_in[5];
    const float* Wp    = (const float*)d_in[6];
    const float* bp    = (const float*)d_in[7];
    float* out = (float*)d_out;

    const int N = in_sizes[0] / 128;   // 100000
    const int E = in_sizes[1] / 2;     // 1600000
    const int* src = edges;
    const int* tgt = edges + E;

    char* ws = (char*)d_ws;
    size_t off = 0;
    auto alloc = [&](size_t bytes) {
        char* p = ws + off;
        off = (off + bytes + 255) & ~(size_t)255;
        return p;
    };
    int*      deg       = (int*)alloc((size_t)N * 4);
    int*      offsets   = (int*)alloc((size_t)(N + 1) * 4);
    int*      blockSums = (int*)alloc(1024 * 4);
    int*      csr       = (int*)alloc((size_t)E * 4);
    ushort16* xb        = (ushort16*)alloc((size_t)N * 128 * 2);
    ushort16* hb1       = (ushort16*)alloc((size_t)N * 128 * 2);
    float*    bufA      = (float*)alloc((size_t)N * 128 * 4);   // combined (GEMM input)
    float*    bufB      = (float*)alloc((size_t)N * 128 * 4);   // h1 fp32
    int*      rank      = (int*)bufA;  // alias: dead before agg writes bufA
    (void)ws_size;

    const int nb = (N + 1023) / 1024;
    const int n8 = N * 16;  // N*128/8
    const int E4 = E / 4;
    const int tail = E - E4 * 4;
    const int rankThreads = E4 + (tail ? 1 : 0);

    hipMemsetAsync(deg, 0, (size_t)N * 4, stream);
    cvt_bf16_kernel<<<(n8 + 255) / 256, 256, 0, stream>>>(x, xb, n8);
    rank_kernel<<<(rankThreads + 255) / 256, 256, 0, stream>>>(tgt, deg, rank, E4, tail, E);
    scan1_kernel<<<nb, 256, 0, stream>>>(deg, offsets, blockSums, N);
    scan2_kernel<<<1, 64, 0, stream>>>(blockSums, nb, offsets, N);
    scan3_kernel<<<nb, 256, 0, stream>>>(offsets, blockSums, N);
    fill_kernel<<<(rankThreads + 255) / 256, 256, 0, stream>>>(src, tgt, rank, offsets, csr, E4, tail, E);

    const int aggBlocks  = (N + 3) / 4;
    const int gemmBlocks = (N + 127) / 128;

    // layer 1
    agg_combine_bf16_kernel<<<aggBlocks, 256, 0, stream>>>(x, xb, offsets, csr, bufA, N);
    gemm_kernel<<<gemmBlocks, 256, 0, stream>>>(bufA, W1, b1, N, bufB, hb1,
                                                nullptr, nullptr, nullptr);
    // layer 2
    agg_combine_bf16_kernel<<<aggBlocks, 256, 0, stream>>>(bufB, hb1, offsets, csr, bufA, N);
    // layer 2 GEMM with fused projection -> out
    gemm_kernel<<<gemmBlocks, 256, 0, stream>>>(bufA, W2, b2, N, nullptr, nullptr,
                                                Wp, bp, out);
}

// Round 4
// 454.865 us; speedup vs baseline: 1.5239x; 1.0806x over previous
//
#include <hip/hip_runtime.h>

typedef unsigned int uint32;
typedef unsigned short ushort16;

// ---------------------------------------------------------------------------
// GNN: h1 = relu((x + mean_agg(x)) @ W1 + b1)
//      h2 = relu((h1 + mean_agg(h1)) @ W2 + b2)
//      out = h2 @ Wp + bp
// R4: bf16 self-row (drops 51.2MB fp32 residual stream per agg), bufB
//     eliminated (gemm1 emits bf16 only; total footprint 117MB < 256MB L3),
//     2x-unrolled gather (8 edges in flight per wave).
// ---------------------------------------------------------------------------

__device__ __forceinline__ ushort16 f2bf(float f) {
    uint32 u = __float_as_uint(f);
    u += 0x7fffu + ((u >> 16) & 1u);       // round-to-nearest-even
    return (ushort16)(u >> 16);
}
__device__ __forceinline__ float bfhi(uint32 u) { return __uint_as_float(u & 0xffff0000u); }
__device__ __forceinline__ float bflo(uint32 u) { return __uint_as_float(u << 16); }

__global__ void cvt_bf16_kernel(const float* __restrict__ in, ushort16* __restrict__ out, int n8) {
    int i = blockIdx.x * 256 + threadIdx.x;
    if (i >= n8) return;
    const float4* p = (const float4*)in + 2 * (size_t)i;
    float4 a = p[0], b = p[1];
    uint4 o;
    o.x = (uint32)f2bf(a.x) | ((uint32)f2bf(a.y) << 16);
    o.y = (uint32)f2bf(a.z) | ((uint32)f2bf(a.w) << 16);
    o.z = (uint32)f2bf(b.x) | ((uint32)f2bf(b.y) << 16);
    o.w = (uint32)f2bf(b.z) | ((uint32)f2bf(b.w) << 16);
    ((uint4*)out)[i] = o;
}

// rank[e] = position of edge e within its target's bucket; deg[t] = final count.
__global__ void rank_kernel(const int* __restrict__ tgt, int* __restrict__ deg,
                            int* __restrict__ rank, int E4, int tail, int E) {
    int i = blockIdx.x * 256 + threadIdx.x;
    if (i < E4) {
        int4 t = ((const int4*)tgt)[i];
        int4 r;
        r.x = atomicAdd(&deg[t.x], 1);
        r.y = atomicAdd(&deg[t.y], 1);
        r.z = atomicAdd(&deg[t.z], 1);
        r.w = atomicAdd(&deg[t.w], 1);
        ((int4*)rank)[i] = r;
    } else if (i == E4 && tail) {
        for (int e = E4 * 4; e < E; ++e) rank[e] = atomicAdd(&deg[tgt[e]], 1);
    }
}

__global__ void scan1_kernel(const int* __restrict__ deg, int* __restrict__ excl,
                             int* __restrict__ blockSums, int N) {
    __shared__ int sd[256];
    int tid = threadIdx.x;
    int base = blockIdx.x * 1024 + tid * 4;
    int v0 = 0, v1 = 0, v2 = 0, v3 = 0;
    if (base + 3 < N) {
        int4 t = *(const int4*)&deg[base];
        v0 = t.x; v1 = t.y; v2 = t.z; v3 = t.w;
    } else {
        if (base     < N) v0 = deg[base];
        if (base + 1 < N) v1 = deg[base + 1];
        if (base + 2 < N) v2 = deg[base + 2];
    }
    int sum = v0 + v1 + v2 + v3;
    sd[tid] = sum;
    __syncthreads();
    for (int o = 1; o < 256; o <<= 1) {
        int t = (tid >= o) ? sd[tid - o] : 0;
        __syncthreads();
        sd[tid] += t;
        __syncthreads();
    }
    int run = sd[tid] - sum;
    if (base     < N) excl[base]     = run; run += v0;
    if (base + 1 < N) excl[base + 1] = run; run += v1;
    if (base + 2 < N) excl[base + 2] = run; run += v2;
    if (base + 3 < N) excl[base + 3] = run;
    if (tid == 255) blockSums[blockIdx.x] = sd[255];
}

__global__ void scan2_kernel(int* blockSums, int nb, int* offsets, int N) {
    if (threadIdx.x == 0 && blockIdx.x == 0) {
        int run = 0;
        for (int b = 0; b < nb; ++b) { int t = blockSums[b]; blockSums[b] = run; run += t; }
        offsets[N] = run;
    }
}

__global__ void scan3_kernel(int* __restrict__ offsets, const int* __restrict__ blockSums, int N) {
    int tid = threadIdx.x;
    int base = blockIdx.x * 1024 + tid * 4;
    int bs = blockSums[blockIdx.x];
#pragma unroll
    for (int i = 0; i < 4; ++i) {
        int idx = base + i;
        if (idx < N) offsets[idx] += bs;
    }
}

// atomic-free scatter: csr[offsets[t] + rank[e]] = src[e]
__global__ void fill_kernel(const int* __restrict__ src, const int* __restrict__ tgt,
                            const int* __restrict__ rank, const int* __restrict__ offsets,
                            int* __restrict__ csr, int E4, int tail, int E) {
    int i = blockIdx.x * 256 + threadIdx.x;
    if (i < E4) {
        int4 t = ((const int4*)tgt)[i];
        int4 r = ((const int4*)rank)[i];
        int4 s = ((const int4*)src)[i];
        csr[offsets[t.x] + r.x] = s.x;
        csr[offsets[t.y] + r.y] = s.y;
        csr[offsets[t.z] + r.z] = s.z;
        csr[offsets[t.w] + r.w] = s.w;
    } else if (i == E4 && tail) {
        for (int e = E4 * 4; e < E; ++e) csr[offsets[tgt[e]] + rank[e]] = src[e];
    }
}

// one wave per node; 8 edges in flight per iteration (2x unroll of 4 lane-
// groups x 16 lanes x 16B). Self row read bf16 (no fp32 residual stream).
__global__ __launch_bounds__(256, 4)
void agg_combine_bf16_kernel(const ushort16* __restrict__ hb,
                             const int* __restrict__ offsets, const int* __restrict__ csr,
                             float* __restrict__ out, int N) {
    int wid = (blockIdx.x * 256 + threadIdx.x) >> 6;
    int lane = threadIdx.x & 63;
    if (wid >= N) return;
    int g = lane >> 4, sl = lane & 15;
    int s0 = offsets[wid];
    int deg = offsets[wid + 1] - s0;
    int fi = sl * 4 + g;
    // self row element pair (issued early; L2-hot from gather traffic)
    uint32 su = ((const uint32*)hb)[(size_t)wid * 64 + fi];

    float acc[8];
#pragma unroll
    for (int j = 0; j < 8; ++j) acc[j] = 0.f;

    int base = 0;
    for (; base + 8 <= deg; base += 8) {
        int i0 = csr[s0 + base + g];
        int i1 = csr[s0 + base + 4 + g];
        uint4 v0 = *(const uint4*)(hb + (size_t)i0 * 128 + sl * 8);
        uint4 v1 = *(const uint4*)(hb + (size_t)i1 * 128 + sl * 8);
        acc[0] += bflo(v0.x); acc[1] += bfhi(v0.x);
        acc[2] += bflo(v0.y); acc[3] += bfhi(v0.y);
        acc[4] += bflo(v0.z); acc[5] += bfhi(v0.z);
        acc[6] += bflo(v0.w); acc[7] += bfhi(v0.w);
        acc[0] += bflo(v1.x); acc[1] += bfhi(v1.x);
        acc[2] += bflo(v1.y); acc[3] += bfhi(v1.y);
        acc[4] += bflo(v1.z); acc[5] += bfhi(v1.z);
        acc[6] += bflo(v1.w); acc[7] += bfhi(v1.w);
    }
    for (; base < deg; base += 4) {
        int e = base + g;
        if (e < deg) {
            int s = csr[s0 + e];
            uint4 v = *(const uint4*)(hb + (size_t)s * 128 + sl * 8);
            acc[0] += bflo(v.x); acc[1] += bfhi(v.x);
            acc[2] += bflo(v.y); acc[3] += bfhi(v.y);
            acc[4] += bflo(v.z); acc[5] += bfhi(v.z);
            acc[6] += bflo(v.w); acc[7] += bfhi(v.w);
        }
    }
    // reduce the 4 lane-groups (each holds partials for channels sl*8..sl*8+7)
#pragma unroll
    for (int j = 0; j < 8; ++j) {
        acc[j] += __shfl_xor(acc[j], 16, 64);
        acc[j] += __shfl_xor(acc[j], 32, 64);
    }
    float inv = 1.f / fmaxf((float)deg, 1.f);
    float ax = (g == 0) ? acc[0] : (g == 1) ? acc[2] : (g == 2) ? acc[4] : acc[6];
    float ay = (g == 0) ? acc[1] : (g == 1) ? acc[3] : (g == 2) ? acc[5] : acc[7];
    float2 o;
    o.x = bflo(su) + ax * inv;
    o.y = bfhi(su) + ay * inv;
    ((float2*)out)[(size_t)wid * 64 + fi] = o;
}

// C[M,128] = relu(A[M,128] @ W[128,128] + b)
// outP==null: write bf16 h to outB (and fp32 to outF if non-null)
// outP!=null: fuse out = h @ Wp + bp  (shfl-reduce across 16 lanes per row)
__global__ __launch_bounds__(256, 2)
void gemm_kernel(const float* __restrict__ A, const float* __restrict__ W,
                 const float* __restrict__ bias, int M,
                 float* __restrict__ outF, ushort16* __restrict__ outB,
                 const float* __restrict__ Wp, const float* __restrict__ bp,
                 float* __restrict__ outP) {
    __shared__ float As[128 * 64];
    __shared__ float Ws[64 * 128];
    const int tid = threadIdx.x;
    const int row0 = blockIdx.x * 128;
    const int c0 = (tid & 15) * 8;
    const int r0 = (tid >> 4) * 8;
    float acc[8][8];
#pragma unroll
    for (int i = 0; i < 8; ++i)
#pragma unroll
        for (int j = 0; j < 8; ++j) acc[i][j] = 0.f;

    for (int k0 = 0; k0 < 128; k0 += 64) {
#pragma unroll
        for (int i = 0; i < 8; ++i) {
            int f = tid + i * 256;
            int r = f >> 4;
            int c4 = f & 15;
            float4 v = make_float4(0.f, 0.f, 0.f, 0.f);
            int gr = row0 + r;
            if (gr < M) v = *(const float4*)&A[(size_t)gr * 128 + k0 + c4 * 4];
            *(float4*)&As[r * 64 + c4 * 4] = v;
        }
#pragma unroll
        for (int i = 0; i < 8; ++i) {
            int f = tid + i * 256;
            int kk = f >> 5;
            int c4 = f & 31;
            *(float4*)&Ws[kk * 128 + c4 * 4] = *(const float4*)&W[(size_t)(k0 + kk) * 128 + c4 * 4];
        }
        __syncthreads();

        for (int kk = 0; kk < 64; kk += 4) {
            float4 av[8];
#pragma unroll
            for (int i = 0; i < 8; ++i) av[i] = *(const float4*)&As[(r0 + i) * 64 + kk];
#pragma unroll
            for (int u = 0; u < 4; ++u) {
                float4 w0 = *(const float4*)&Ws[(kk + u) * 128 + c0];
                float4 w1 = *(const float4*)&Ws[(kk + u) * 128 + c0 + 4];
#pragma unroll
                for (int i = 0; i < 8; ++i) {
                    float a = (&av[i].x)[u];
                    acc[i][0] += a * w0.x; acc[i][1] += a * w0.y;
                    acc[i][2] += a * w0.z; acc[i][3] += a * w0.w;
                    acc[i][4] += a * w1.x; acc[i][5] += a * w1.y;
                    acc[i][6] += a * w1.z; acc[i][7] += a * w1.w;
                }
            }
        }
        __syncthreads();
    }

    float4 b0 = *(const float4*)&bias[c0];
    float4 b1 = *(const float4*)&bias[c0 + 4];

    float wp[8][5];
    if (outP) {
#pragma unroll
        for (int c = 0; c < 8; ++c)
#pragma unroll
            for (int j = 0; j < 5; ++j) wp[c][j] = Wp[(c0 + c) * 5 + j];
    }

#pragma unroll
    for (int i = 0; i < 8; ++i) {
        int gr = row0 + r0 + i;
        bool valid = gr < M;
        float o[8];
        o[0] = fmaxf(acc[i][0] + b0.x, 0.f); o[1] = fmaxf(acc[i][1] + b0.y, 0.f);
        o[2] = fmaxf(acc[i][2] + b0.z, 0.f); o[3] = fmaxf(acc[i][3] + b0.w, 0.f);
        o[4] = fmaxf(acc[i][4] + b1.x, 0.f); o[5] = fmaxf(acc[i][5] + b1.y, 0.f);
        o[6] = fmaxf(acc[i][6] + b1.z, 0.f); o[7] = fmaxf(acc[i][7] + b1.w, 0.f);
        if (outP) {
            float p[5];
#pragma unroll
            for (int j = 0; j < 5; ++j) {
                p[j] = o[0] * wp[0][j] + o[1] * wp[1][j] + o[2] * wp[2][j] + o[3] * wp[3][j]
                     + o[4] * wp[4][j] + o[5] * wp[5][j] + o[6] * wp[6][j] + o[7] * wp[7][j];
            }
#pragma unroll
            for (int m = 1; m <= 8; m <<= 1) {
#pragma unroll
                for (int j = 0; j < 5; ++j) p[j] += __shfl_xor(p[j], m, 64);
            }
            if (valid && (tid & 15) == 0) {
#pragma unroll
                for (int j = 0; j < 5; ++j) outP[(size_t)gr * 5 + j] = p[j] + bp[j];
            }
        } else if (valid) {
            if (outF) {
                *(float4*)&outF[(size_t)gr * 128 + c0]     = make_float4(o[0], o[1], o[2], o[3]);
                *(float4*)&outF[(size_t)gr * 128 + c0 + 4] = make_float4(o[4], o[5], o[6], o[7]);
            }
            if (outB) {
                uint4 pk;
                pk.x = (uint32)f2bf(o[0]) | ((uint32)f2bf(o[1]) << 16);
                pk.y = (uint32)f2bf(o[2]) | ((uint32)f2bf(o[3]) << 16);
                pk.z = (uint32)f2bf(o[4]) | ((uint32)f2bf(o[5]) << 16);
                pk.w = (uint32)f2bf(o[6]) | ((uint32)f2bf(o[7]) << 16);
                *(uint4*)(outB + (size_t)gr * 128 + c0) = pk;
            }
        }
    }
}

extern "C" void kernel_launch(void* const* d_in, const int* in_sizes, int n_in,
                              void* d_out, int out_size, void* d_ws, size_t ws_size,
                              hipStream_t stream) {
    const float* x     = (const float*)d_in[0];
    const int*   edges = (const int*)d_in[1];
    const float* W1    = (const float*)d_in[2];
    const float* b1    = (const float*)d_in[3];
    const float* W2    = (const float*)d_in[4];
    const float* b2    = (const float*)d_in[5];
    const float* Wp    = (const float*)d_in[6];
    const float* bp    = (const float*)d_in[7];
    float* out = (float*)d_out;

    const int N = in_sizes[0] / 128;   // 100000
    const int E = in_sizes[1] / 2;     // 1600000
    const int* src = edges;
    const int* tgt = edges + E;

    char* ws = (char*)d_ws;
    size_t off = 0;
    auto alloc = [&](size_t bytes) {
        char* p = ws + off;
        off = (off + bytes + 255) & ~(size_t)255;
        return p;
    };
    int*      deg       = (int*)alloc((size_t)N * 4);
    int*      offsets   = (int*)alloc((size_t)(N + 1) * 4);
    int*      blockSums = (int*)alloc(1024 * 4);
    int*      csr       = (int*)alloc((size_t)E * 4);
    ushort16* xb        = (ushort16*)alloc((size_t)N * 128 * 2);
    ushort16* hb1       = (ushort16*)alloc((size_t)N * 128 * 2);
    float*    bufA      = (float*)alloc((size_t)N * 128 * 4);   // combined (GEMM input)
    int*      rank      = (int*)bufA;  // alias: dead before agg writes bufA
    (void)ws_size;

    const int nb = (N + 1023) / 1024;
    const int n8 = N * 16;  // N*128/8
    const int E4 = E / 4;
    const int tail = E - E4 * 4;
    const int rankThreads = E4 + (tail ? 1 : 0);

    hipMemsetAsync(deg, 0, (size_t)N * 4, stream);
    cvt_bf16_kernel<<<(n8 + 255) / 256, 256, 0, stream>>>(x, xb, n8);
    rank_kernel<<<(rankThreads + 255) / 256, 256, 0, stream>>>(tgt, deg, rank, E4, tail, E);
    scan1_kernel<<<nb, 256, 0, stream>>>(deg, offsets, blockSums, N);
    scan2_kernel<<<1, 64, 0, stream>>>(blockSums, nb, offsets, N);
    scan3_kernel<<<nb, 256, 0, stream>>>(offsets, blockSums, N);
    fill_kernel<<<(rankThreads + 255) / 256, 256, 0, stream>>>(src, tgt, rank, offsets, csr, E4, tail, E);

    const int aggBlocks  = (N + 3) / 4;
    const int gemmBlocks = (N + 127) / 128;

    // layer 1 (self + gather both from xb)
    agg_combine_bf16_kernel<<<aggBlocks, 256, 0, stream>>>(xb, offsets, csr, bufA, N);
    gemm_kernel<<<gemmBlocks, 256, 0, stream>>>(bufA, W1, b1, N, nullptr, hb1,
                                                nullptr, nullptr, nullptr);
    // layer 2 (self + gather both from hb1)
    agg_combine_bf16_kernel<<<aggBlocks, 256, 0, stream>>>(hb1, offsets, csr, bufA, N);
    // layer 2 GEMM with fused projection -> out
    gemm_kernel<<<gemmBlocks, 256, 0, stream>>>(bufA, W2, b2, N, nullptr, nullptr,
                                                Wp, bp, out);
}